// Round 13
// baseline (162.942 us; speedup 1.0000x reference)
//
#include <hip/hip_runtime.h>
#include <hip/hip_bf16.h>

#define SEQ 14
#define IN 24
#define H 64
#define CLS 10
#define NBATCH 65536
// 2*log2(e): folds tanh's 2*v AND exp->exp2 into the f32 weight/bias prescale.
#define WSCALE 2.8853900817779268f

typedef __attribute__((ext_vector_type(4))) float f32x4;
typedef __attribute__((ext_vector_type(8))) short bf16x8;

#define MFMA(A, B, C) __builtin_amdgcn_mfma_f32_16x16x32_bf16(A, B, C, 0, 0, 0)
// Anti-rematerialization pin (R5-verified).
#define PIN(v) asm volatile("" : "+v"(v))

static __device__ __forceinline__ float fexp2(float x) {
#if __has_builtin(__builtin_amdgcn_exp2f)
    return __builtin_amdgcn_exp2f(x);   // v_exp_f32 (2^x)
#else
    return __expf(x * 0.6931471805599453f);
#endif
}
// y = 2*v*log2(e) (prescaled weights): tanh(v) = 1 - 2/(2^y + 1)
static __device__ __forceinline__ float tanh2(float y) {
    float e = fexp2(y);
    return fmaf(-2.0f, __builtin_amdgcn_rcpf(e + 1.0f), 1.0f);
}
static __device__ __forceinline__ short f2bf(float f) {
    __hip_bfloat16 h = __float2bfloat16(f);
    union { __hip_bfloat16 h; short s; } u; u.h = h;
    return u.s;
}
static __device__ __forceinline__ bf16x8 pack8(f32x4 a, f32x4 b) {
    bf16x8 r;
    r[0] = f2bf(a[0]); r[1] = f2bf(a[1]); r[2] = f2bf(a[2]); r[3] = f2bf(a[3]);
    r[4] = f2bf(b[0]); r[5] = f2bf(b[1]); r[6] = f2bf(b[2]); r[7] = f2bf(b[3]);
    return r;
}
static __device__ __forceinline__ bf16x8 loadw8(const float* p) {
    return pack8(*(const f32x4*)p, *(const f32x4*)(p + 4));
}
static __device__ __forceinline__ bf16x8 loadw8s(const float* p, float s) {
    f32x4 a = *(const f32x4*)p, b = *(const f32x4*)(p + 4);
    return pack8(a * s, b * s);
}
// Row permutation making the D->B repack lane-local:
//   G(m, ri) = 32*(m>>1) + 8*(ri>>2) + 4*(m&1) + (ri&3)   (bijection on 0..63)
// D tile m, lane(g,c), reg r => global row G(m, 4g+r) = 32(m>>1)+8g+4(m&1)+r.
// Those 16 values per lane are EXACTLY the rows its own B-frags need:
//   Bf[m>>1] elements 4*(m&1)+r = th[m][r].   (derived + spot-checked)
static __device__ __forceinline__ int Grow(int m, int ri) {
    return 32 * (m >> 1) + 8 * (ri >> 2) + 4 * (m & 1) + (ri & 3);
}

// Register-resident n-split: block = 256 thr = 4 INDEPENDENT waves; each wave
// owns 16 batch cols through all 3 layers and all T. No barriers in the loop,
// no LDS repack (row-permuted weights make D->B a register rename), no
// cross-wave/lane traffic. Weights fully replicated per wave (bf16, pinned);
// x prefetched one step ahead; L1/L2 biases in a tiny LDS broadcast table.
// B/x/head frag maps are R6-verified; A/bias/store rows use Grow().
__global__ __launch_bounds__(256, 1) void rnn_reg(
    const float* __restrict__ x,     // [B, T, 24]
    const float* __restrict__ h0in,  // [3, B, 64]
    const float* __restrict__ pWi0, const float* __restrict__ pWh0,
    const float* __restrict__ pbi0, const float* __restrict__ pbh0,
    const float* __restrict__ pWi1, const float* __restrict__ pWh1,
    const float* __restrict__ pbi1, const float* __restrict__ pbh1,
    const float* __restrict__ pWi2, const float* __restrict__ pWh2,
    const float* __restrict__ pbi2, const float* __restrict__ pbh2,
    const float* __restrict__ pWout, const float* __restrict__ pbout,
    float* __restrict__ out)         // [B*10] ++ [3*B*64]
{
    __shared__ float blds[2][H];     // L1/L2 scaled biases (natural row order)

    const int tid  = threadIdx.x;
    const int lane = tid & 63;
    const int g    = lane >> 4;      // k-group 0..3
    const int c    = lane & 15;      // col-in-tile / A-row-in-tile
    const int w    = tid >> 6;       // wave id 0..3 (independent)
    const int bc   = blockIdx.x * 64 + w * 16;   // this wave's batch col base

    if (tid < 128) {
        const int l = tid >> 6, j = tid & 63;
        blds[l][j] = WSCALE * ((l ? pbi2 : pbi1)[j] + (l ? pbh2 : pbh1)[j]);
    }

    // ---- weights, fully replicated per wave, row-permuted, pinned ----
    bf16x8 aWh0[4][2], aWi1[4][2], aWh1[4][2], aWi2[4][2], aWh2[4][2], aWi0[4];
#pragma unroll
    for (int m = 0; m < 4; ++m) {
        const int row = Grow(m, c);
#pragma unroll
        for (int f = 0; f < 2; ++f) {
            aWh0[m][f] = loadw8s(pWh0 + row * H + 32 * f + 8 * g, WSCALE); PIN(aWh0[m][f]);
            aWi1[m][f] = loadw8s(pWi1 + row * H + 32 * f + 8 * g, WSCALE); PIN(aWi1[m][f]);
            aWh1[m][f] = loadw8s(pWh1 + row * H + 32 * f + 8 * g, WSCALE); PIN(aWh1[m][f]);
            aWi2[m][f] = loadw8s(pWi2 + row * H + 32 * f + 8 * g, WSCALE); PIN(aWi2[m][f]);
            aWh2[m][f] = loadw8s(pWh2 + row * H + 32 * f + 8 * g, WSCALE); PIN(aWh2[m][f]);
        }
        if (g < 3) {
            aWi0[m] = loadw8s(pWi0 + row * IN + 8 * g, WSCALE);
        } else {
#pragma unroll
            for (int j = 0; j < 8; ++j) aWi0[m][j] = 0;
            aWi0[m][0] = f2bf(WSCALE * (pbi0[row] + pbh0[row]));  // bias @ k=24
        }
        PIN(aWi0[m]);
    }

    // ---- h state as B-frags (registers; R6-verified load pattern) ----
    bf16x8 h0f[2], h1f[2], h2f[2];
#pragma unroll
    for (int f = 0; f < 2; ++f) {
        h0f[f] = loadw8(h0in + ((size_t)0 * NBATCH + bc + c) * H + 32 * f + 8 * g);
        h1f[f] = loadw8(h0in + ((size_t)1 * NBATCH + bc + c) * H + 32 * f + 8 * g);
        h2f[f] = loadw8(h0in + ((size_t)2 * NBATCH + bc + c) * H + 32 * f + 8 * g);
    }

    // ---- x prefetch (t=0) ----
    const float* xb = x + (size_t)(bc + c) * (SEQ * IN) + 8 * g;
    f32x4 xra, xrb;
    if (g < 3) { xra = *(const f32x4*)xb; xrb = *(const f32x4*)(xb + 4); }

    float* hsout = out + (size_t)NBATCH * CLS;
    __syncthreads();   // blds ready (the only barrier)

#pragma unroll 1
    for (int t = 0; t < SEQ; ++t) {
        // ---------------- L0: x + h0 -> h0' ----------------
        {
            bf16x8 xB;
#pragma unroll
            for (int j = 0; j < 8; ++j) xB[j] = 0;
            if (g < 3) {
                xB = pack8(xra, xrb);
                if (t + 1 < SEQ) {   // prefetch x[t+1] under this interval
                    const float* xp = xb + (t + 1) * IN;
                    xra = *(const f32x4*)xp; xrb = *(const f32x4*)(xp + 4);
                }
            } else {
                xB[0] = (short)0x3F80;   // 1.0 -> multiplies baked bias @ k=24
            }
            bf16x8 n0, n1;
#pragma unroll
            for (int m = 0; m < 4; ++m) {
                f32x4 acc = {0.f, 0.f, 0.f, 0.f};
                acc = MFMA(aWh0[m][0], h0f[0], acc);
                acc = MFMA(aWh0[m][1], h0f[1], acc);
                acc = MFMA(aWi0[m], xB, acc);
                f32x4 th;
#pragma unroll
                for (int r = 0; r < 4; ++r) th[r] = tanh2(acc[r]);
                if (t == SEQ - 1)
                    *(f32x4*)(hsout + (size_t)(bc + c) * H +
                              32 * (m >> 1) + 8 * g + 4 * (m & 1)) = th;
#pragma unroll
                for (int r = 0; r < 4; ++r) {
                    if (m < 2) n0[4 * (m & 1) + r] = f2bf(th[r]);
                    else       n1[4 * (m & 1) + r] = f2bf(th[r]);
                }
            }
            h0f[0] = n0; h0f[1] = n1;
        }
        // ---------------- L1 / L2 (bias from LDS broadcast) ----------------
#define LAYER(li, hS, hB_, aWhX, aWiX)                                          \
        {                                                                       \
            bf16x8 n0, n1;                                                      \
            _Pragma("unroll")                                                   \
            for (int m = 0; m < 4; ++m) {                                       \
                f32x4 acc = *(const f32x4*)&blds[li - 1]                        \
                    [32 * (m >> 1) + 8 * g + 4 * (m & 1)];                      \
                acc = MFMA(aWhX[m][0], hS[0], acc);                             \
                acc = MFMA(aWhX[m][1], hS[1], acc);                             \
                acc = MFMA(aWiX[m][0], hB_[0], acc);                            \
                acc = MFMA(aWiX[m][1], hB_[1], acc);                            \
                f32x4 th;                                                       \
                _Pragma("unroll")                                               \
                for (int r = 0; r < 4; ++r) th[r] = tanh2(acc[r]);              \
                if (t == SEQ - 1)                                               \
                    *(f32x4*)(hsout + (size_t)(li) * NBATCH * H +               \
                              (size_t)(bc + c) * H +                            \
                              32 * (m >> 1) + 8 * g + 4 * (m & 1)) = th;        \
                _Pragma("unroll")                                               \
                for (int r = 0; r < 4; ++r) {                                   \
                    if (m < 2) n0[4 * (m & 1) + r] = f2bf(th[r]);               \
                    else       n1[4 * (m & 1) + r] = f2bf(th[r]);               \
                }                                                               \
            }                                                                   \
            hS[0] = n0; hS[1] = n1;                                             \
        }
        LAYER(1, h1f, h0f, aWh1, aWi1)
        LAYER(2, h2f, h1f, aWh2, aWi2)
#undef LAYER
    }

    // ---------------- logits head (R6-verified pattern) ----------------
    {
        bf16x8 aWo[2];
#pragma unroll
        for (int f = 0; f < 2; ++f) {
            if (c < CLS) {
                aWo[f] = loadw8(pWout + c * H + 32 * f + 8 * g);  // unscaled
            } else {
#pragma unroll
                for (int j = 0; j < 8; ++j) aWo[f][j] = 0;
            }
        }
        f32x4 acc = {0.f, 0.f, 0.f, 0.f};
        acc = MFMA(aWo[0], h2f[0], acc);
        acc = MFMA(aWo[1], h2f[1], acc);
#pragma unroll
        for (int r = 0; r < 4; ++r) {
            const int cls = 4 * g + r;
            if (cls < CLS)
                out[(size_t)(bc + c) * CLS + cls] = acc[r] + pbout[cls];
        }
    }
}

extern "C" void kernel_launch(void* const* d_in, const int* in_sizes, int n_in,
                              void* d_out, int out_size, void* d_ws, size_t ws_size,
                              hipStream_t stream) {
    const float* x    = (const float*)d_in[0];
    const float* h0in = (const float*)d_in[1];
    const float* Wi0  = (const float*)d_in[2];
    const float* Wh0  = (const float*)d_in[3];
    const float* bi0  = (const float*)d_in[4];
    const float* bh0  = (const float*)d_in[5];
    const float* Wi1  = (const float*)d_in[6];
    const float* Wh1  = (const float*)d_in[7];
    const float* bi1  = (const float*)d_in[8];
    const float* bh1  = (const float*)d_in[9];
    const float* Wi2  = (const float*)d_in[10];
    const float* Wh2  = (const float*)d_in[11];
    const float* bi2  = (const float*)d_in[12];
    const float* bh2  = (const float*)d_in[13];
    const float* Wout = (const float*)d_in[14];
    const float* bout = (const float*)d_in[15];
    float* out = (float*)d_out;

    dim3 grid(NBATCH / 64), block(256);
    rnn_reg<<<grid, block, 0, stream>>>(x, h0in, Wi0, Wh0, bi0, bh0,
                                        Wi1, Wh1, bi1, bh1,
                                        Wi2, Wh2, bi2, bh2,
                                        Wout, bout, out);
}

// Round 14
// 107.408 us; speedup vs baseline: 1.5170x; 1.5170x over previous
//
#include <hip/hip_runtime.h>
#include <hip/hip_bf16.h>

#define SEQ 14
#define IN 24
#define H 64
#define CLS 10
#define NBATCH 65536
#define NB 32   // batch elems per block
// 2*log2(e): folds tanh's 2*v AND exp->exp2 into the f32 weight/bias prescale.
#define WSCALE 2.8853900817779268f

typedef __attribute__((ext_vector_type(4))) float f32x4;
typedef __attribute__((ext_vector_type(8))) short bf16x8;
typedef __attribute__((ext_vector_type(4))) short bf16x4;

#define MFMA(A, B, C) __builtin_amdgcn_mfma_f32_16x16x32_bf16(A, B, C, 0, 0, 0)
// Anti-rematerialization pin (R5-verified).
#define PIN(v) asm volatile("" : "+v"(v))

static __device__ __forceinline__ float fexp2(float x) {
#if __has_builtin(__builtin_amdgcn_exp2f)
    return __builtin_amdgcn_exp2f(x);   // v_exp_f32 (2^x)
#else
    return __expf(x * 0.6931471805599453f);
#endif
}
// y = 2*v*log2(e) (prescaled weights): tanh(v) = 1 - 2/(2^y + 1)
static __device__ __forceinline__ float tanh2(float y) {
    float e = fexp2(y);
    return fmaf(-2.0f, __builtin_amdgcn_rcpf(e + 1.0f), 1.0f);
}
static __device__ __forceinline__ short f2bf(float f) {
    __hip_bfloat16 h = __float2bfloat16(f);
    union { __hip_bfloat16 h; short s; } u; u.h = h;
    return u.s;
}
static __device__ __forceinline__ bf16x8 pack8(f32x4 a, f32x4 b) {
    bf16x8 r;
    r[0] = f2bf(a[0]); r[1] = f2bf(a[1]); r[2] = f2bf(a[2]); r[3] = f2bf(a[3]);
    r[4] = f2bf(b[0]); r[5] = f2bf(b[1]); r[6] = f2bf(b[2]); r[7] = f2bf(b[3]);
    return r;
}
static __device__ __forceinline__ bf16x8 loadw8(const float* p) {
    return pack8(*(const f32x4*)p, *(const f32x4*)(p + 4));
}
static __device__ __forceinline__ bf16x8 loadw8s(const float* p, float s) {
    f32x4 a = *(const f32x4*)p, b = *(const f32x4*)(p + 4);
    return pack8(a * s, b * s);
}

// R11 skewed skeleton + 2D wave split: wave (mi,ni) owns rows [32mi,32mi+32)
// x cols [16ni,16ni+16). Per section: 4 ds_read_b128 (vs R11's 8) -- the
// 4x cross-wave LDS duplication becomes 2x -- at the cost of 2x weight regs
// (112 pinned/wave, R10 level). Skew: interval s = {L0(s), L1(s-1), L2(s-2)},
// 16 barriers. Parity: reads at s hit (s+1)&1, writes s&1; h_l(init) at
// parity (l+1)&1. Frag maps (R3+ HW-verified): A row=c, k=32f+8g+j;
// B col=c, same k; D col=c, row=4g+r. Repack: kg=4mi+2mtl+(g>>1), e=4(g&1)+r.
__global__ __launch_bounds__(256, 2) void rnn_mfma(
    const float* __restrict__ x,     // [B, T, 24]
    const float* __restrict__ h0in,  // [3, B, 64]
    const float* __restrict__ pWi0, const float* __restrict__ pWh0,
    const float* __restrict__ pbi0, const float* __restrict__ pbh0,
    const float* __restrict__ pWi1, const float* __restrict__ pWh1,
    const float* __restrict__ pbi1, const float* __restrict__ pbh1,
    const float* __restrict__ pWi2, const float* __restrict__ pWh2,
    const float* __restrict__ pbi2, const float* __restrict__ pbh2,
    const float* __restrict__ pWout, const float* __restrict__ pbout,
    float* __restrict__ out)         // [B*10] ++ [3*B*64]
{
    __shared__ __align__(16) short hbuf[2][3][8][NB][8];  // 24 KB

    const int tid  = threadIdx.x;
    const int lane = tid & 63;
    const int g    = lane >> 4;      // k-group 0..3
    const int c    = lane & 15;      // col-in-n-tile / A-row-in-tile
    const int wid  = tid >> 6;
    const int mi   = wid >> 1;       // row-half 0..1 (rows 32mi..32mi+31)
    const int ni   = wid & 1;        // col-half 0..1 (cols 16ni..16ni+15)
    const int cc   = c + 16 * ni;    // this lane's batch col within block
    const int b0   = blockIdx.x * NB;

    // ---- preload h_l(init) -> hbuf[(l+1)&1][l] (bf16) ----
    {
        const int b = tid & 31, k8 = (tid >> 5) & 7;
#pragma unroll
        for (int l = 0; l < 3; ++l) {
            const float* p = h0in + ((size_t)l * NBATCH + (b0 + b)) * H + k8 * 8;
            *(bf16x8*)&hbuf[(l + 1) & 1][l][k8][b][0] =
                pack8(*(const f32x4*)p, *(const f32x4*)(p + 4));
        }
    }

    // ---- weight A-fragments: 2 m-subtiles (rows 32mi+16mtl+c), pinned ----
    bf16x8 aWh0[2][2], aWi1[2][2], aWh1[2][2], aWi2[2][2], aWh2[2][2], aWi0[2];
#pragma unroll
    for (int mtl = 0; mtl < 2; ++mtl) {
        const int row = 32 * mi + 16 * mtl + c;
#pragma unroll
        for (int kt = 0; kt < 2; ++kt) {
            aWh0[mtl][kt] = loadw8s(pWh0 + row * H + kt * 32 + g * 8, WSCALE); PIN(aWh0[mtl][kt]);
            aWi1[mtl][kt] = loadw8s(pWi1 + row * H + kt * 32 + g * 8, WSCALE); PIN(aWi1[mtl][kt]);
            aWh1[mtl][kt] = loadw8s(pWh1 + row * H + kt * 32 + g * 8, WSCALE); PIN(aWh1[mtl][kt]);
            aWi2[mtl][kt] = loadw8s(pWi2 + row * H + kt * 32 + g * 8, WSCALE); PIN(aWi2[mtl][kt]);
            aWh2[mtl][kt] = loadw8s(pWh2 + row * H + kt * 32 + g * 8, WSCALE); PIN(aWh2[mtl][kt]);
        }
        if (g < 3) aWi0[mtl] = loadw8s(pWi0 + row * IN + g * 8, WSCALE);
        else {
#pragma unroll
            for (int j = 0; j < 8; ++j) aWi0[mtl][j] = 0;   // k=24..31 zero pad
        }
        PIN(aWi0[mtl]);
    }

    // ---- scaled bias acc-init vectors (rows 32mi+16mtl+4g..+3), pinned ----
    f32x4 bs0[2], bs1[2], bs2[2];
#pragma unroll
    for (int mtl = 0; mtl < 2; ++mtl) {
        const int i0 = 32 * mi + 16 * mtl + 4 * g;
        bs0[mtl] = (*(const f32x4*)(pbi0 + i0) + *(const f32x4*)(pbh0 + i0)) * WSCALE;
        bs1[mtl] = (*(const f32x4*)(pbi1 + i0) + *(const f32x4*)(pbh1 + i0)) * WSCALE;
        bs2[mtl] = (*(const f32x4*)(pbi2 + i0) + *(const f32x4*)(pbh2 + i0)) * WSCALE;
        PIN(bs0[mtl]); PIN(bs1[mtl]); PIN(bs2[mtl]);
    }

    const int eb = (g & 1) * 4;          // repack write elem base
    const float* xb = x + (size_t)(b0 + cc) * (SEQ * IN) + g * 8;
    float* hsout = out + (size_t)NBATCH * CLS;

    __syncthreads();

// ---- layer-step macros; s_ determines parities: read (s_+1)&1, write s_&1.
#define L0S(s_)                                                                 \
    {                                                                           \
        const int pr = ((s_) + 1) & 1, pw = (s_) & 1, t = (s_);                 \
        bf16x8 xB;                                                              \
        _Pragma("unroll")                                                       \
        for (int j = 0; j < 8; ++j) xB[j] = 0;                                  \
        if (g < 3) {                                                            \
            const float* xp = xb + t * IN;                                      \
            xB = pack8(*(const f32x4*)xp, *(const f32x4*)(xp + 4));             \
        }                                                                       \
        bf16x8 s0 = *(const bf16x8*)&hbuf[pr][0][g][cc][0];                     \
        bf16x8 s1 = *(const bf16x8*)&hbuf[pr][0][4 + g][cc][0];                 \
        _Pragma("unroll")                                                       \
        for (int mtl = 0; mtl < 2; ++mtl) {                                     \
            f32x4 acc = bs0[mtl];                                               \
            acc = MFMA(aWh0[mtl][0], s0, acc);                                  \
            acc = MFMA(aWh0[mtl][1], s1, acc);                                  \
            acc = MFMA(aWi0[mtl], xB, acc);                                     \
            f32x4 th;                                                           \
            _Pragma("unroll")                                                   \
            for (int r = 0; r < 4; ++r) th[r] = tanh2(acc[r]);                  \
            if (t == SEQ - 1)                                                   \
                *(f32x4*)(hsout + (size_t)(b0 + cc) * H +                       \
                          32 * mi + 16 * mtl + 4 * g) = th;                     \
            bf16x4 pv;                                                          \
            _Pragma("unroll")                                                   \
            for (int r = 0; r < 4; ++r) pv[r] = f2bf(th[r]);                    \
            *(bf16x4*)&hbuf[pw][0][4 * mi + 2 * mtl + (g >> 1)][cc][eb] = pv;   \
        }                                                                       \
    }

#define L12S(s_, li, bsv, aWhX, aWiX)                                           \
    {                                                                           \
        const int pr = ((s_) + 1) & 1, pw = (s_) & 1, t = (s_) - (li);          \
        bf16x8 s0 = *(const bf16x8*)&hbuf[pr][li][g][cc][0];                    \
        bf16x8 s1 = *(const bf16x8*)&hbuf[pr][li][4 + g][cc][0];                \
        bf16x8 u0 = *(const bf16x8*)&hbuf[pr][li - 1][g][cc][0];                \
        bf16x8 u1 = *(const bf16x8*)&hbuf[pr][li - 1][4 + g][cc][0];            \
        _Pragma("unroll")                                                       \
        for (int mtl = 0; mtl < 2; ++mtl) {                                     \
            f32x4 acc = bsv[mtl];                                               \
            acc = MFMA(aWhX[mtl][0], s0, acc);                                  \
            acc = MFMA(aWhX[mtl][1], s1, acc);                                  \
            acc = MFMA(aWiX[mtl][0], u0, acc);                                  \
            acc = MFMA(aWiX[mtl][1], u1, acc);                                  \
            f32x4 th;                                                           \
            _Pragma("unroll")                                                   \
            for (int r = 0; r < 4; ++r) th[r] = tanh2(acc[r]);                  \
            if (t == SEQ - 1)                                                   \
                *(f32x4*)(hsout + (size_t)(li) * NBATCH * H +                   \
                          (size_t)(b0 + cc) * H +                               \
                          32 * mi + 16 * mtl + 4 * g) = th;                     \
            bf16x4 pv;                                                          \
            _Pragma("unroll")                                                   \
            for (int r = 0; r < 4; ++r) pv[r] = f2bf(th[r]);                    \
            *(bf16x4*)&hbuf[pw][li][4 * mi + 2 * mtl + (g >> 1)][cc][eb] = pv;  \
        }                                                                       \
    }

    // ---- prologue: s=0, s=1 ----
    L0S(0);
    __syncthreads();
    L0S(1);
    L12S(1, 1, bs1, aWh1, aWi1);
    __syncthreads();

    // ---- main loop: s=2..SEQ-1 (straight-line 3-layer body, 1 barrier) ----
#pragma unroll 1
    for (int s = 2; s < SEQ; ++s) {
        L0S(s);
        L12S(s, 1, bs1, aWh1, aWi1);
        L12S(s, 2, bs2, aWh2, aWi2);
        __syncthreads();
    }

    // ---- epilogue: s=SEQ (14), s=SEQ+1 (15) ----
    L12S(SEQ, 1, bs1, aWh1, aWi1);
    L12S(SEQ, 2, bs2, aWh2, aWi2);
    __syncthreads();
    L12S(SEQ + 1, 2, bs2, aWh2, aWi2);
    __syncthreads();

#undef L0S
#undef L12S

    // ===== logits head (mi==0 waves; ni picks col-half). h2 parity 1. =====
    if (mi == 0) {
        bf16x8 aWo0, aWo1;
#pragma unroll
        for (int j = 0; j < 8; ++j) { aWo0[j] = 0; aWo1[j] = 0; }
        if (c < CLS) {
            aWo0 = loadw8(pWout + c * H + 8 * g);         // unscaled: no tanh
            aWo1 = loadw8(pWout + c * H + 32 + 8 * g);
        }
        bf16x8 s0 = *(const bf16x8*)&hbuf[1][2][g][cc][0];
        bf16x8 s1 = *(const bf16x8*)&hbuf[1][2][4 + g][cc][0];
        f32x4 acc = {0.f, 0.f, 0.f, 0.f};
        acc = MFMA(aWo0, s0, acc);
        acc = MFMA(aWo1, s1, acc);
#pragma unroll
        for (int r = 0; r < 4; ++r) {
            const int cls = 4 * g + r;
            if (cls < CLS)
                out[(size_t)(b0 + cc) * CLS + cls] = acc[r] + pbout[cls];
        }
    }
}

extern "C" void kernel_launch(void* const* d_in, const int* in_sizes, int n_in,
                              void* d_out, int out_size, void* d_ws, size_t ws_size,
                              hipStream_t stream) {
    const float* x    = (const float*)d_in[0];
    const float* h0in = (const float*)d_in[1];
    const float* Wi0  = (const float*)d_in[2];
    const float* Wh0  = (const float*)d_in[3];
    const float* bi0  = (const float*)d_in[4];
    const float* bh0  = (const float*)d_in[5];
    const float* Wi1  = (const float*)d_in[6];
    const float* Wh1  = (const float*)d_in[7];
    const float* bi1  = (const float*)d_in[8];
    const float* bh1  = (const float*)d_in[9];
    const float* Wi2  = (const float*)d_in[10];
    const float* Wh2  = (const float*)d_in[11];
    const float* bi2  = (const float*)d_in[12];
    const float* bh2  = (const float*)d_in[13];
    const float* Wout = (const float*)d_in[14];
    const float* bout = (const float*)d_in[15];
    float* out = (float*)d_out;

    dim3 grid(NBATCH / NB), block(256);
    rnn_mfma<<<grid, block, 0, stream>>>(x, h0in, Wi0, Wh0, bi0, bh0,
                                         Wi1, Wh1, bi1, bh1,
                                         Wi2, Wh2, bi2, bh2,
                                         Wout, bout, out);
}

// Round 15
// 98.466 us; speedup vs baseline: 1.6548x; 1.0908x over previous
//
#include <hip/hip_runtime.h>
#include <hip/hip_bf16.h>

#define SEQ 14
#define IN 24
#define H 64
#define CLS 10
#define NBATCH 65536
#define NB 32   // batch elems per block (best measured geometry)
// 2*log2(e): folds tanh's 2*v AND exp->exp2 into the f32 weight/bias prescale.
#define WSCALE 2.8853900817779268f

typedef __attribute__((ext_vector_type(4))) float f32x4;
typedef __attribute__((ext_vector_type(8))) short bf16x8;
typedef __attribute__((ext_vector_type(4))) short bf16x4;

#define MFMA(A, B, C) __builtin_amdgcn_mfma_f32_16x16x32_bf16(A, B, C, 0, 0, 0)
// Anti-rematerialization pin (R5-verified).
#define PIN(v) asm volatile("" : "+v"(v))
// Interval barrier: lgkmcnt(0) only (LDS ordering is the ONLY cross-wave
// dependency; x loads are wave-private, h-state stores are global-only).
// Avoids __syncthreads' vmcnt(0) drain so prefetched x / pending stores stay
// in flight across barriers (T4 pattern, m139/m201).
#define BAR()                                                \
    do {                                                     \
        asm volatile("s_waitcnt lgkmcnt(0)" ::: "memory");   \
        __builtin_amdgcn_s_barrier();                        \
    } while (0)

static __device__ __forceinline__ float fexp2(float x) {
#if __has_builtin(__builtin_amdgcn_exp2f)
    return __builtin_amdgcn_exp2f(x);   // v_exp_f32 (2^x)
#else
    return __expf(x * 0.6931471805599453f);
#endif
}
// y = 2*v*log2(e) (prescaled weights): tanh(v) = 1 - 2/(2^y + 1)
static __device__ __forceinline__ float tanh2(float y) {
    float e = fexp2(y);
    return fmaf(-2.0f, __builtin_amdgcn_rcpf(e + 1.0f), 1.0f);
}
static __device__ __forceinline__ short f2bf(float f) {
    __hip_bfloat16 h = __float2bfloat16(f);
    union { __hip_bfloat16 h; short s; } u; u.h = h;
    return u.s;
}
static __device__ __forceinline__ bf16x8 pack8(f32x4 a, f32x4 b) {
    bf16x8 r;
    r[0] = f2bf(a[0]); r[1] = f2bf(a[1]); r[2] = f2bf(a[2]); r[3] = f2bf(a[3]);
    r[4] = f2bf(b[0]); r[5] = f2bf(b[1]); r[6] = f2bf(b[2]); r[7] = f2bf(b[3]);
    return r;
}
static __device__ __forceinline__ bf16x8 loadw8(const float* p) {
    return pack8(*(const f32x4*)p, *(const f32x4*)(p + 4));
}
static __device__ __forceinline__ bf16x8 loadw8s(const float* p, float s) {
    f32x4 a = *(const f32x4*)p, b = *(const f32x4*)(p + 4);
    return pack8(a * s, b * s);
}

// R11 skewed skeleton (best: 92 us): 4 waves m-split, interval s =
// {L0(s), L1(s-1), L2(s-2)}, 16 barriers. NEW vs R11: lgkm-only barriers +
// x prefetched one interval ahead (now effective since barriers don't drain
// vmcnt). Parity: reads at s hit (s+1)&1, writes s&1; h_l(init) at (l+1)&1.
// Frag maps (R3+ HW-verified): A row=c, k=32f+8g+j; B col=c, same k;
// D col=c, row=4g+r. Repack: kg=2mt+(g>>1), e=4(g&1)+r.
__global__ __launch_bounds__(256, 2) void rnn_mfma(
    const float* __restrict__ x,     // [B, T, 24]
    const float* __restrict__ h0in,  // [3, B, 64]
    const float* __restrict__ pWi0, const float* __restrict__ pWh0,
    const float* __restrict__ pbi0, const float* __restrict__ pbh0,
    const float* __restrict__ pWi1, const float* __restrict__ pWh1,
    const float* __restrict__ pbi1, const float* __restrict__ pbh1,
    const float* __restrict__ pWi2, const float* __restrict__ pWh2,
    const float* __restrict__ pbi2, const float* __restrict__ pbh2,
    const float* __restrict__ pWout, const float* __restrict__ pbout,
    float* __restrict__ out)         // [B*10] ++ [3*B*64]
{
    __shared__ __align__(16) short hbuf[2][3][8][NB][8];  // 24 KB

    const int tid  = threadIdx.x;
    const int lane = tid & 63;
    const int g    = lane >> 4;      // k-group 0..3
    const int c    = lane & 15;      // col-in-n-tile / A-row-in-tile
    const int mt   = tid >> 6;       // wave id = m-tile 0..3
    const int b0   = blockIdx.x * NB;

    // ---- preload h_l(init) -> hbuf[(l+1)&1][l] (bf16) ----
    {
        const int b = tid & 31, k8 = (tid >> 5) & 7;
#pragma unroll
        for (int l = 0; l < 3; ++l) {
            const float* p = h0in + ((size_t)l * NBATCH + (b0 + b)) * H + k8 * 8;
            *(bf16x8*)&hbuf[(l + 1) & 1][l][k8][b][0] =
                pack8(*(const f32x4*)p, *(const f32x4*)(p + 4));
        }
    }

    // ---- weight A-fragments (bf16, prescaled, pinned) ----
    const int ia = mt * 16 + c;
    bf16x8 aWi0;
    if (g < 3) aWi0 = loadw8s(pWi0 + ia * IN + g * 8, WSCALE);
    else {
#pragma unroll
        for (int j = 0; j < 8; ++j) aWi0[j] = 0;   // k = 24..31 zero pad
    }
    PIN(aWi0);
    bf16x8 aWh0[2], aWi1[2], aWh1[2], aWi2[2], aWh2[2];
#pragma unroll
    for (int kt = 0; kt < 2; ++kt) {
        aWh0[kt] = loadw8s(pWh0 + ia * H + kt * 32 + g * 8, WSCALE);  PIN(aWh0[kt]);
        aWi1[kt] = loadw8s(pWi1 + ia * H + kt * 32 + g * 8, WSCALE);  PIN(aWi1[kt]);
        aWh1[kt] = loadw8s(pWh1 + ia * H + kt * 32 + g * 8, WSCALE);  PIN(aWh1[kt]);
        aWi2[kt] = loadw8s(pWi2 + ia * H + kt * 32 + g * 8, WSCALE);  PIN(aWi2[kt]);
        aWh2[kt] = loadw8s(pWh2 + ia * H + kt * 32 + g * 8, WSCALE);  PIN(aWh2[kt]);
    }

    // ---- scaled bias acc-init vectors, pinned ----
    const int i0 = mt * 16 + g * 4;
    f32x4 bs0 = (*(const f32x4*)(pbi0 + i0) + *(const f32x4*)(pbh0 + i0)) * WSCALE;
    f32x4 bs1 = (*(const f32x4*)(pbi1 + i0) + *(const f32x4*)(pbh1 + i0)) * WSCALE;
    f32x4 bs2 = (*(const f32x4*)(pbi2 + i0) + *(const f32x4*)(pbh2 + i0)) * WSCALE;
    PIN(bs0); PIN(bs1); PIN(bs2);

    const int kgw = mt * 2 + (g >> 1);   // repack write kg
    const int eb  = (g & 1) * 4;         // repack write elem base

    const float* xb0 = x + (size_t)(b0 + c) * (SEQ * IN) + g * 8;        // nt0
    const float* xb1 = x + (size_t)(b0 + 16 + c) * (SEQ * IN) + g * 8;   // nt1
    float* hsout = out + (size_t)NBATCH * CLS;

    // ---- x prefetch registers: x[t] raw f32 (valid for g<3 lanes) ----
    f32x4 xr0a, xr0b, xr1a, xr1b;
    if (g < 3) {
        xr0a = *(const f32x4*)(xb0);      xr0b = *(const f32x4*)(xb0 + 4);
        xr1a = *(const f32x4*)(xb1);      xr1b = *(const f32x4*)(xb1 + 4);
    }

    __syncthreads();   // initial full barrier (preload visibility)

// ---- layer-step macros; s_ determines parities: read (s_+1)&1, write s_&1.
#define L0S(s_)                                                                 \
    {                                                                           \
        const int pr = ((s_) + 1) & 1, pw = (s_) & 1, t = (s_);                 \
        bf16x8 bx0, bx1;                                                        \
        _Pragma("unroll")                                                       \
        for (int j = 0; j < 8; ++j) { bx0[j] = 0; bx1[j] = 0; }                 \
        if (g < 3) {                                                            \
            bx0 = pack8(xr0a, xr0b);                                            \
            bx1 = pack8(xr1a, xr1b);                                            \
            if (t + 1 < SEQ) {   /* prefetch x[t+1]; lands across BAR() */      \
                const float* p0 = xb0 + (t + 1) * IN;                           \
                const float* p1 = xb1 + (t + 1) * IN;                           \
                xr0a = *(const f32x4*)p0;  xr0b = *(const f32x4*)(p0 + 4);      \
                xr1a = *(const f32x4*)p1;  xr1b = *(const f32x4*)(p1 + 4);      \
            }                                                                   \
        }                                                                       \
        bf16x8 s0a = *(const bf16x8*)&hbuf[pr][0][g][c][0];                     \
        bf16x8 s0b = *(const bf16x8*)&hbuf[pr][0][g][c + 16][0];                \
        bf16x8 s1a = *(const bf16x8*)&hbuf[pr][0][4 + g][c][0];                 \
        bf16x8 s1b = *(const bf16x8*)&hbuf[pr][0][4 + g][c + 16][0];            \
        f32x4 a0 = bs0, a1 = bs0;                                               \
        a0 = MFMA(aWh0[0], s0a, a0);  a1 = MFMA(aWh0[0], s0b, a1);              \
        a0 = MFMA(aWh0[1], s1a, a0);  a1 = MFMA(aWh0[1], s1b, a1);              \
        a0 = MFMA(aWi0,    bx0, a0);  a1 = MFMA(aWi0,    bx1, a1);              \
        f32x4 t0, t1;                                                           \
        _Pragma("unroll")                                                       \
        for (int r = 0; r < 4; ++r) { t0[r] = tanh2(a0[r]); t1[r] = tanh2(a1[r]); } \
        if (t == SEQ - 1) {                                                     \
            *(f32x4*)(hsout + (size_t)(b0 + c) * H + i0) = t0;                  \
            *(f32x4*)(hsout + (size_t)(b0 + 16 + c) * H + i0) = t1;             \
        }                                                                       \
        bf16x4 p0v, p1v;                                                        \
        _Pragma("unroll")                                                       \
        for (int r = 0; r < 4; ++r) { p0v[r] = f2bf(t0[r]); p1v[r] = f2bf(t1[r]); } \
        *(bf16x4*)&hbuf[pw][0][kgw][c][eb] = p0v;                               \
        *(bf16x4*)&hbuf[pw][0][kgw][c + 16][eb] = p1v;                          \
    }

#define L12S(s_, li, bsv, aWhX, aWiX)                                           \
    {                                                                           \
        const int pr = ((s_) + 1) & 1, pw = (s_) & 1, t = (s_) - (li);          \
        bf16x8 s0a = *(const bf16x8*)&hbuf[pr][li][g][c][0];                    \
        bf16x8 s0b = *(const bf16x8*)&hbuf[pr][li][g][c + 16][0];               \
        bf16x8 s1a = *(const bf16x8*)&hbuf[pr][li][4 + g][c][0];                \
        bf16x8 s1b = *(const bf16x8*)&hbuf[pr][li][4 + g][c + 16][0];           \
        bf16x8 b0a = *(const bf16x8*)&hbuf[pr][li - 1][g][c][0];                \
        bf16x8 b0b = *(const bf16x8*)&hbuf[pr][li - 1][g][c + 16][0];           \
        bf16x8 b1a = *(const bf16x8*)&hbuf[pr][li - 1][4 + g][c][0];            \
        bf16x8 b1b = *(const bf16x8*)&hbuf[pr][li - 1][4 + g][c + 16][0];       \
        f32x4 a0 = bsv, a1 = bsv;                                               \
        a0 = MFMA(aWhX[0], s0a, a0);  a1 = MFMA(aWhX[0], s0b, a1);              \
        a0 = MFMA(aWhX[1], s1a, a0);  a1 = MFMA(aWhX[1], s1b, a1);              \
        a0 = MFMA(aWiX[0], b0a, a0);  a1 = MFMA(aWiX[0], b0b, a1);              \
        a0 = MFMA(aWiX[1], b1a, a0);  a1 = MFMA(aWiX[1], b1b, a1);              \
        f32x4 t0, t1;                                                           \
        _Pragma("unroll")                                                       \
        for (int r = 0; r < 4; ++r) { t0[r] = tanh2(a0[r]); t1[r] = tanh2(a1[r]); } \
        if (t == SEQ - 1) {                                                     \
            float* hp = hsout + (size_t)(li) * NBATCH * H;                      \
            *(f32x4*)(hp + (size_t)(b0 + c) * H + i0) = t0;                     \
            *(f32x4*)(hp + (size_t)(b0 + 16 + c) * H + i0) = t1;                \
        }                                                                       \
        bf16x4 p0v, p1v;                                                        \
        _Pragma("unroll")                                                       \
        for (int r = 0; r < 4; ++r) { p0v[r] = f2bf(t0[r]); p1v[r] = f2bf(t1[r]); } \
        *(bf16x4*)&hbuf[pw][li][kgw][c][eb] = p0v;                              \
        *(bf16x4*)&hbuf[pw][li][kgw][c + 16][eb] = p1v;                         \
    }

    // ---- prologue: s=0, s=1 ----
    L0S(0);
    BAR();
    L0S(1);
    L12S(1, 1, bs1, aWh1, aWi1);
    BAR();

    // ---- main loop: s=2..SEQ-1 (straight-line 3-layer body, 1 barrier) ----
#pragma unroll 1
    for (int s = 2; s < SEQ; ++s) {
        L0S(s);
        L12S(s, 1, bs1, aWh1, aWi1);
        L12S(s, 2, bs2, aWh2, aWi2);
        BAR();
    }

    // ---- epilogue: s=SEQ (14), s=SEQ+1 (15) ----
    L12S(SEQ, 1, bs1, aWh1, aWi1);
    L12S(SEQ, 2, bs2, aWh2, aWi2);
    BAR();
    L12S(SEQ + 1, 2, bs2, aWh2, aWi2);
    BAR();

#undef L0S
#undef L12S

    // ===== logits head (MFMA, waves 0-1). Final h2 in parity (SEQ+1)&1 = 1.
    if (mt < 2) {
        bf16x8 aWo0, aWo1;
#pragma unroll
        for (int j = 0; j < 8; ++j) { aWo0[j] = 0; aWo1[j] = 0; }
        if (c < CLS) {
            aWo0 = loadw8(pWout + c * H + 8 * g);         // unscaled: no tanh
            aWo1 = loadw8(pWout + c * H + 32 + 8 * g);
        }
        const int col = c + 16 * mt;
        bf16x8 s0 = *(const bf16x8*)&hbuf[1][2][g][col][0];
        bf16x8 s1 = *(const bf16x8*)&hbuf[1][2][4 + g][col][0];
        f32x4 acc = {0.f, 0.f, 0.f, 0.f};
        acc = MFMA(aWo0, s0, acc);
        acc = MFMA(aWo1, s1, acc);
#pragma unroll
        for (int r = 0; r < 4; ++r) {
            const int cls = 4 * g + r;
            if (cls < CLS)
                out[(size_t)(b0 + col) * CLS + cls] = acc[r] + pbout[cls];
        }
    }
}

extern "C" void kernel_launch(void* const* d_in, const int* in_sizes, int n_in,
                              void* d_out, int out_size, void* d_ws, size_t ws_size,
                              hipStream_t stream) {
    const float* x    = (const float*)d_in[0];
    const float* h0in = (const float*)d_in[1];
    const float* Wi0  = (const float*)d_in[2];
    const float* Wh0  = (const float*)d_in[3];
    const float* bi0  = (const float*)d_in[4];
    const float* bh0  = (const float*)d_in[5];
    const float* Wi1  = (const float*)d_in[6];
    const float* Wh1  = (const float*)d_in[7];
    const float* bi1  = (const float*)d_in[8];
    const float* bh1  = (const float*)d_in[9];
    const float* Wi2  = (const float*)d_in[10];
    const float* Wh2  = (const float*)d_in[11];
    const float* bi2  = (const float*)d_in[12];
    const float* bh2  = (const float*)d_in[13];
    const float* Wout = (const float*)d_in[14];
    const float* bout = (const float*)d_in[15];
    float* out = (float*)d_out;

    dim3 grid(NBATCH / NB), block(256);
    rnn_mfma<<<grid, block, 0, stream>>>(x, h0in, Wi0, Wh0, bi0, bh0,
                                         Wi1, Wh1, bi1, bh1,
                                         Wi2, Wh2, bi2, bh2,
                                         Wout, bout, out);
}

// Round 16
// 92.302 us; speedup vs baseline: 1.7653x; 1.0668x over previous
//
#include <hip/hip_runtime.h>
#include <hip/hip_bf16.h>

#define SEQ 14
#define IN 24
#define H 64
#define CLS 10
#define NBATCH 65536
#define NB 32   // batch elems per block (best measured geometry)
// 2*log2(e): folds tanh's 2*v AND exp->exp2 into the f32 weight/bias prescale.
#define WSCALE 2.8853900817779268f

typedef __attribute__((ext_vector_type(4))) float f32x4;
typedef __attribute__((ext_vector_type(8))) short bf16x8;
typedef __attribute__((ext_vector_type(4))) short bf16x4;

#define MFMA(A, B, C) __builtin_amdgcn_mfma_f32_16x16x32_bf16(A, B, C, 0, 0, 0)
// Anti-rematerialization pin (R5-verified).
#define PIN(v) asm volatile("" : "+v"(v))
// Interval barrier: lgkmcnt(0) only (LDS ordering is the ONLY cross-wave
// dependency; x loads are wave-private, h-state stores are global-only).
// Avoids __syncthreads' vmcnt(0) drain. R15 verified SAFE (absmax unchanged);
// this round isolates it WITHOUT R15's x-prefetch (the prefetch was the
// regression: +16 f32 live-range in an AGPR-pressure-limited kernel).
#define BAR()                                                \
    do {                                                     \
        asm volatile("s_waitcnt lgkmcnt(0)" ::: "memory");   \
        __builtin_amdgcn_s_barrier();                        \
    } while (0)

static __device__ __forceinline__ float fexp2(float x) {
#if __has_builtin(__builtin_amdgcn_exp2f)
    return __builtin_amdgcn_exp2f(x);   // v_exp_f32 (2^x)
#else
    return __expf(x * 0.6931471805599453f);
#endif
}
// y = 2*v*log2(e) (prescaled weights): tanh(v) = 1 - 2/(2^y + 1)
static __device__ __forceinline__ float tanh2(float y) {
    float e = fexp2(y);
    return fmaf(-2.0f, __builtin_amdgcn_rcpf(e + 1.0f), 1.0f);
}
static __device__ __forceinline__ short f2bf(float f) {
    __hip_bfloat16 h = __float2bfloat16(f);
    union { __hip_bfloat16 h; short s; } u; u.h = h;
    return u.s;
}
static __device__ __forceinline__ bf16x8 pack8(f32x4 a, f32x4 b) {
    bf16x8 r;
    r[0] = f2bf(a[0]); r[1] = f2bf(a[1]); r[2] = f2bf(a[2]); r[3] = f2bf(a[3]);
    r[4] = f2bf(b[0]); r[5] = f2bf(b[1]); r[6] = f2bf(b[2]); r[7] = f2bf(b[3]);
    return r;
}
static __device__ __forceinline__ bf16x8 loadw8(const float* p) {
    return pack8(*(const f32x4*)p, *(const f32x4*)(p + 4));
}
static __device__ __forceinline__ bf16x8 loadw8s(const float* p, float s) {
    f32x4 a = *(const f32x4*)p, b = *(const f32x4*)(p + 4);
    return pack8(a * s, b * s);
}

// R11 skewed skeleton (best: 92 us): 4 waves m-split, interval s =
// {L0(s), L1(s-1), L2(s-2)}, 16 barriers. ONLY change vs R11: lgkm-only
// interval barriers (no vmcnt drain). NO x-prefetch (R12/R15 showed it
// costs ~6 us of residency). Parity: reads at s hit (s+1)&1, writes s&1;
// h_l(init) at (l+1)&1. Frag maps (R3+ HW-verified): A row=c, k=32f+8g+j;
// B col=c, same k; D col=c, row=4g+r. Repack: kg=2mt+(g>>1), e=4(g&1)+r.
__global__ __launch_bounds__(256, 2) void rnn_mfma(
    const float* __restrict__ x,     // [B, T, 24]
    const float* __restrict__ h0in,  // [3, B, 64]
    const float* __restrict__ pWi0, const float* __restrict__ pWh0,
    const float* __restrict__ pbi0, const float* __restrict__ pbh0,
    const float* __restrict__ pWi1, const float* __restrict__ pWh1,
    const float* __restrict__ pbi1, const float* __restrict__ pbh1,
    const float* __restrict__ pWi2, const float* __restrict__ pWh2,
    const float* __restrict__ pbi2, const float* __restrict__ pbh2,
    const float* __restrict__ pWout, const float* __restrict__ pbout,
    float* __restrict__ out)         // [B*10] ++ [3*B*64]
{
    __shared__ __align__(16) short hbuf[2][3][8][NB][8];  // 24 KB

    const int tid  = threadIdx.x;
    const int lane = tid & 63;
    const int g    = lane >> 4;      // k-group 0..3
    const int c    = lane & 15;      // col-in-n-tile / A-row-in-tile
    const int mt   = tid >> 6;       // wave id = m-tile 0..3
    const int b0   = blockIdx.x * NB;

    // ---- preload h_l(init) -> hbuf[(l+1)&1][l] (bf16) ----
    {
        const int b = tid & 31, k8 = (tid >> 5) & 7;
#pragma unroll
        for (int l = 0; l < 3; ++l) {
            const float* p = h0in + ((size_t)l * NBATCH + (b0 + b)) * H + k8 * 8;
            *(bf16x8*)&hbuf[(l + 1) & 1][l][k8][b][0] =
                pack8(*(const f32x4*)p, *(const f32x4*)(p + 4));
        }
    }

    // ---- weight A-fragments (bf16, prescaled, pinned) ----
    const int ia = mt * 16 + c;
    bf16x8 aWi0;
    if (g < 3) aWi0 = loadw8s(pWi0 + ia * IN + g * 8, WSCALE);
    else {
#pragma unroll
        for (int j = 0; j < 8; ++j) aWi0[j] = 0;   // k = 24..31 zero pad
    }
    PIN(aWi0);
    bf16x8 aWh0[2], aWi1[2], aWh1[2], aWi2[2], aWh2[2];
#pragma unroll
    for (int kt = 0; kt < 2; ++kt) {
        aWh0[kt] = loadw8s(pWh0 + ia * H + kt * 32 + g * 8, WSCALE);  PIN(aWh0[kt]);
        aWi1[kt] = loadw8s(pWi1 + ia * H + kt * 32 + g * 8, WSCALE);  PIN(aWi1[kt]);
        aWh1[kt] = loadw8s(pWh1 + ia * H + kt * 32 + g * 8, WSCALE);  PIN(aWh1[kt]);
        aWi2[kt] = loadw8s(pWi2 + ia * H + kt * 32 + g * 8, WSCALE);  PIN(aWi2[kt]);
        aWh2[kt] = loadw8s(pWh2 + ia * H + kt * 32 + g * 8, WSCALE);  PIN(aWh2[kt]);
    }

    // ---- scaled bias acc-init vectors, pinned ----
    const int i0 = mt * 16 + g * 4;
    f32x4 bs0 = (*(const f32x4*)(pbi0 + i0) + *(const f32x4*)(pbh0 + i0)) * WSCALE;
    f32x4 bs1 = (*(const f32x4*)(pbi1 + i0) + *(const f32x4*)(pbh1 + i0)) * WSCALE;
    f32x4 bs2 = (*(const f32x4*)(pbi2 + i0) + *(const f32x4*)(pbh2 + i0)) * WSCALE;
    PIN(bs0); PIN(bs1); PIN(bs2);

    const int kgw = mt * 2 + (g >> 1);   // repack write kg
    const int eb  = (g & 1) * 4;         // repack write elem base

    const float* xb0 = x + (size_t)(b0 + c) * (SEQ * IN) + g * 8;        // nt0
    const float* xb1 = x + (size_t)(b0 + 16 + c) * (SEQ * IN) + g * 8;   // nt1
    float* hsout = out + (size_t)NBATCH * CLS;

    __syncthreads();   // initial full barrier (preload visibility)

// ---- layer-step macros; s_ determines parities: read (s_+1)&1, write s_&1.
#define L0S(s_)                                                                 \
    {                                                                           \
        const int pr = ((s_) + 1) & 1, pw = (s_) & 1, t = (s_);                 \
        bf16x8 bx0, bx1;                                                        \
        _Pragma("unroll")                                                       \
        for (int j = 0; j < 8; ++j) { bx0[j] = 0; bx1[j] = 0; }                 \
        if (g < 3) {                                                            \
            const float* p0 = xb0 + t * IN;                                     \
            const float* p1 = xb1 + t * IN;                                     \
            bx0 = pack8(*(const f32x4*)p0, *(const f32x4*)(p0 + 4));            \
            bx1 = pack8(*(const f32x4*)p1, *(const f32x4*)(p1 + 4));            \
        }                                                                       \
        bf16x8 s0a = *(const bf16x8*)&hbuf[pr][0][g][c][0];                     \
        bf16x8 s0b = *(const bf16x8*)&hbuf[pr][0][g][c + 16][0];                \
        bf16x8 s1a = *(const bf16x8*)&hbuf[pr][0][4 + g][c][0];                 \
        bf16x8 s1b = *(const bf16x8*)&hbuf[pr][0][4 + g][c + 16][0];            \
        f32x4 a0 = bs0, a1 = bs0;                                               \
        a0 = MFMA(aWh0[0], s0a, a0);  a1 = MFMA(aWh0[0], s0b, a1);              \
        a0 = MFMA(aWh0[1], s1a, a0);  a1 = MFMA(aWh0[1], s1b, a1);              \
        a0 = MFMA(aWi0,    bx0, a0);  a1 = MFMA(aWi0,    bx1, a1);              \
        f32x4 t0, t1;                                                           \
        _Pragma("unroll")                                                       \
        for (int r = 0; r < 4; ++r) { t0[r] = tanh2(a0[r]); t1[r] = tanh2(a1[r]); } \
        if (t == SEQ - 1) {                                                     \
            *(f32x4*)(hsout + (size_t)(b0 + c) * H + i0) = t0;                  \
            *(f32x4*)(hsout + (size_t)(b0 + 16 + c) * H + i0) = t1;             \
        }                                                                       \
        bf16x4 p0v, p1v;                                                        \
        _Pragma("unroll")                                                       \
        for (int r = 0; r < 4; ++r) { p0v[r] = f2bf(t0[r]); p1v[r] = f2bf(t1[r]); } \
        *(bf16x4*)&hbuf[pw][0][kgw][c][eb] = p0v;                               \
        *(bf16x4*)&hbuf[pw][0][kgw][c + 16][eb] = p1v;                          \
    }

#define L12S(s_, li, bsv, aWhX, aWiX)                                           \
    {                                                                           \
        const int pr = ((s_) + 1) & 1, pw = (s_) & 1, t = (s_) - (li);          \
        bf16x8 s0a = *(const bf16x8*)&hbuf[pr][li][g][c][0];                    \
        bf16x8 s0b = *(const bf16x8*)&hbuf[pr][li][g][c + 16][0];               \
        bf16x8 s1a = *(const bf16x8*)&hbuf[pr][li][4 + g][c][0];                \
        bf16x8 s1b = *(const bf16x8*)&hbuf[pr][li][4 + g][c + 16][0];           \
        bf16x8 b0a = *(const bf16x8*)&hbuf[pr][li - 1][g][c][0];                \
        bf16x8 b0b = *(const bf16x8*)&hbuf[pr][li - 1][g][c + 16][0];           \
        bf16x8 b1a = *(const bf16x8*)&hbuf[pr][li - 1][4 + g][c][0];            \
        bf16x8 b1b = *(const bf16x8*)&hbuf[pr][li - 1][4 + g][c + 16][0];       \
        f32x4 a0 = bsv, a1 = bsv;                                               \
        a0 = MFMA(aWhX[0], s0a, a0);  a1 = MFMA(aWhX[0], s0b, a1);              \
        a0 = MFMA(aWhX[1], s1a, a0);  a1 = MFMA(aWhX[1], s1b, a1);              \
        a0 = MFMA(aWiX[0], b0a, a0);  a1 = MFMA(aWiX[0], b0b, a1);              \
        a0 = MFMA(aWiX[1], b1a, a0);  a1 = MFMA(aWiX[1], b1b, a1);              \
        f32x4 t0, t1;                                                           \
        _Pragma("unroll")                                                       \
        for (int r = 0; r < 4; ++r) { t0[r] = tanh2(a0[r]); t1[r] = tanh2(a1[r]); } \
        if (t == SEQ - 1) {                                                     \
            float* hp = hsout + (size_t)(li) * NBATCH * H;                      \
            *(f32x4*)(hp + (size_t)(b0 + c) * H + i0) = t0;                     \
            *(f32x4*)(hp + (size_t)(b0 + 16 + c) * H + i0) = t1;                \
        }                                                                       \
        bf16x4 p0v, p1v;                                                        \
        _Pragma("unroll")                                                       \
        for (int r = 0; r < 4; ++r) { p0v[r] = f2bf(t0[r]); p1v[r] = f2bf(t1[r]); } \
        *(bf16x4*)&hbuf[pw][li][kgw][c][eb] = p0v;                              \
        *(bf16x4*)&hbuf[pw][li][kgw][c + 16][eb] = p1v;                         \
    }

    // ---- prologue: s=0, s=1 ----
    L0S(0);
    BAR();
    L0S(1);
    L12S(1, 1, bs1, aWh1, aWi1);
    BAR();

    // ---- main loop: s=2..SEQ-1 (straight-line 3-layer body, 1 barrier) ----
#pragma unroll 1
    for (int s = 2; s < SEQ; ++s) {
        L0S(s);
        L12S(s, 1, bs1, aWh1, aWi1);
        L12S(s, 2, bs2, aWh2, aWi2);
        BAR();
    }

    // ---- epilogue: s=SEQ (14), s=SEQ+1 (15) ----
    L12S(SEQ, 1, bs1, aWh1, aWi1);
    L12S(SEQ, 2, bs2, aWh2, aWi2);
    BAR();
    L12S(SEQ + 1, 2, bs2, aWh2, aWi2);
    BAR();

#undef L0S
#undef L12S

    // ===== logits head (MFMA, waves 0-1). Final h2 in parity (SEQ+1)&1 = 1.
    if (mt < 2) {
        bf16x8 aWo0, aWo1;
#pragma unroll
        for (int j = 0; j < 8; ++j) { aWo0[j] = 0; aWo1[j] = 0; }
        if (c < CLS) {
            aWo0 = loadw8(pWout + c * H + 8 * g);         // unscaled: no tanh
            aWo1 = loadw8(pWout + c * H + 32 + 8 * g);
        }
        const int col = c + 16 * mt;
        bf16x8 s0 = *(const bf16x8*)&hbuf[1][2][g][col][0];
        bf16x8 s1 = *(const bf16x8*)&hbuf[1][2][4 + g][col][0];
        f32x4 acc = {0.f, 0.f, 0.f, 0.f};
        acc = MFMA(aWo0, s0, acc);
        acc = MFMA(aWo1, s1, acc);
#pragma unroll
        for (int r = 0; r < 4; ++r) {
            const int cls = 4 * g + r;
            if (cls < CLS)
                out[(size_t)(b0 + col) * CLS + cls] = acc[r] + pbout[cls];
        }
    }
}

extern "C" void kernel_launch(void* const* d_in, const int* in_sizes, int n_in,
                              void* d_out, int out_size, void* d_ws, size_t ws_size,
                              hipStream_t stream) {
    const float* x    = (const float*)d_in[0];
    const float* h0in = (const float*)d_in[1];
    const float* Wi0  = (const float*)d_in[2];
    const float* Wh0  = (const float*)d_in[3];
    const float* bi0  = (const float*)d_in[4];
    const float* bh0  = (const float*)d_in[5];
    const float* Wi1  = (const float*)d_in[6];
    const float* Wh1  = (const float*)d_in[7];
    const float* bi1  = (const float*)d_in[8];
    const float* bh1  = (const float*)d_in[9];
    const float* Wi2  = (const float*)d_in[10];
    const float* Wh2  = (const float*)d_in[11];
    const float* bi2  = (const float*)d_in[12];
    const float* bh2  = (const float*)d_in[13];
    const float* Wout = (const float*)d_in[14];
    const float* bout = (const float*)d_in[15];
    float* out = (float*)d_out;

    dim3 grid(NBATCH / NB), block(256);
    rnn_mfma<<<grid, block, 0, stream>>>(x, h0in, Wi0, Wh0, bi0, bh0,
                                         Wi1, Wh1, bi1, bh1,
                                         Wi2, Wh2, bi2, bh2,
                                         Wout, bout, out);
}